// Round 21
// baseline (126.205 us; speedup 1.0000x reference)
//
#include <hip/hip_runtime.h>

#define KK 32
#define KP 33
#define NMAXC 256
#define BCH 32            // bsz * ENS
#define NPADC 32768
#define TARGETC 32640
#define LSEG 64           // items per segment
#define MSEG 512          // NPADC / LSEG
#define GSZ 32            // segments per group
#define NG 16             // MSEG / GSZ
#define SS 2

#define OFFS(i) ((i)*255 - (i)*((i)-1)/2)

// ---- cross-lane helpers on the VALU pipe (no ds_bpermute) ----
__device__ __forceinline__ int dpp_shr1_i(int v) {
    // wave_shr:1 (0x138), bound_ctrl=1 -> lane 0 receives 0
    return __builtin_amdgcn_mov_dpp(v, 0x138, 0xf, 0xf, true);
}
__device__ __forceinline__ unsigned dpp_shr1_u(unsigned v) {
    return (unsigned)dpp_shr1_i((int)v);
}
__device__ __forceinline__ double dpp_shr1_d(double v) {
    union { double d; int i[2]; } u; u.d = v;
    u.i[0] = dpp_shr1_i(u.i[0]);
    u.i[1] = dpp_shr1_i(u.i[1]);
    return u.d;
}
__device__ __forceinline__ double readlane_d(double v, int l) {
    union { double d; int i[2]; } u; u.d = v;
    union { double d; int i[2]; } r;
    r.i[0] = __builtin_amdgcn_readlane(u.i[0], l);
    r.i[1] = __builtin_amdgcn_readlane(u.i[1], l);
    return r.d;
}

__device__ __forceinline__ void decode_ij(int t, int& oi, int& oj) {
    int ii = (int)((511.0 - sqrt(511.0 * 511.0 - 8.0 * (double)t)) * 0.5);
    if (ii < 0) ii = 0;
    if (ii > 254) ii = 254;
    while (ii < 254 && OFFS(ii + 1) <= t) ++ii;
    while (ii > 0 && OFFS(ii) > t) --ii;
    oi = ii;
    oj = t - OFFS(ii) + ii + 1;
}

// 33-point truncated polynomial product: out[r] = sum_j a[j]*b[r-j].
__device__ __forceinline__ double conv33_rb(double a_dep, double b_rot) {
    double s0 = 0.0, s1 = 0.0, s2 = 0.0, s3 = 0.0;
    double brot = b_rot;
#pragma unroll
    for (int j = 0; j < KP; ++j) {
        double aj = readlane_d(a_dep, j);
        switch (j & 3) {
            case 0: s0 = fma(aj, brot, s0); break;
            case 1: s1 = fma(aj, brot, s1); break;
            case 2: s2 = fma(aj, brot, s2); break;
            default: s3 = fma(aj, brot, s3); break;
        }
        brot = dpp_shr1_d(brot);
    }
    return (s0 + s1) + (s2 + s3);
}

// ---- kernel 1: fused exp(theta) + segment polys + within-group suffix scan
__global__ void k_prepscan(const float* __restrict__ sc, double* __restrict__ X,
                           double* __restrict__ sfxI, double* __restrict__ gpoly) {
    __shared__ double bpl[GSZ][KP];       // 8448 B
    int tid = threadIdx.x;                // 1024
    int lane = tid & 63;
    int w = tid >> 6;                     // 0..15
    int blk = blockIdx.x;                 // b*NG + g
    int b = blk / NG, g = blk % NG;
#pragma unroll
    for (int q = 0; q < 2; ++q) {
        int seg = g * GSZ + w * 2 + q;    // segment index within chain b
        int t = seg * LSEG + lane;
        double x = 0.0;
        if (t < TARGETC) {
            int i, j;
            decode_ij(t, i, j);
            double th = (double)sc[((size_t)b * NMAXC + i) * NMAXC + j] +
                        (double)sc[((size_t)b * NMAXC + j) * NMAXC + i];
            x = exp(th);
        }
        X[(size_t)b * NPADC + t] = x;
        double c = (lane == 0) ? 1.0 : 0.0;
#pragma unroll
        for (int j = 0; j < LSEG; ++j) {
            double xj = readlane_d(x, j);
            double up = dpp_shr1_d(c);    // lane0 -> 0
            c = fma(xj, up, c);
        }
        if (lane < KP) bpl[w * 2 + q][lane] = c;
    }
    __syncthreads();
    if (w == 0) {                         // phase B: serial suffix scan, old order
        double run = (lane == 0) ? 1.0 : 0.0;
        for (int i = GSZ - 1; i >= 0; --i) {
            double bp = (lane < KP) ? bpl[i][lane] : 0.0;
            run = conv33_rb(run, bp);
            if (lane < KP) sfxI[((size_t)b * MSEG + g * GSZ + i) * KP + lane] = run;
        }
        if (lane < KP) gpoly[(size_t)blk * KP + lane] = run;
    }
}

// ---- kernel 2: two roles.
//      blockIdx.x < BCH : suffix scan over group polys + full Z poly (wave 0)
//      blockIdx.x >= BCH: coalesced LDS-tile U transpose/widen -> UT[s][b][t]
__global__ void __launch_bounds__(1024) k_gscan(
        const float* __restrict__ U, const double* __restrict__ gpoly,
        double* __restrict__ gcarry, double* __restrict__ eZ,
        double* __restrict__ UT) {
    __shared__ float ut[LSEG][KP];        // 8448 B (transpose role)
    int tid = threadIdx.x;
    if ((int)blockIdx.x >= BCH) {
        // ---- transpose role: 4 tiles of 64t x 32b, coalesced both sides ----
        int q = blockIdx.x - BCH;         // 0..255
#pragma unroll
        for (int k = 0; k < 4; ++k) {
            int p = q * 4 + k;            // tile id: s = p>>9, t0 = (p&511)*64
            int s = p >> 9, t0 = (p & 511) * LSEG;
            int e = tid * 2;              // load: 2 consecutive f32 per thread
            int tr = e >> 5, bb = e & 31;
            float2 v = *reinterpret_cast<const float2*>(
                &U[((size_t)s * NPADC + t0 + tr) * BCH + bb]);
            ut[tr][bb] = v.x;
            ut[tr][bb + 1] = v.y;
            __syncthreads();
#pragma unroll
            for (int kk = 0; kk < 2; ++kk) {   // store: 2 f64 per thread, coalesced
                int e2 = tid + kk * 1024;
                int bb2 = e2 >> 6, tt = e2 & 63;
                UT[((size_t)s * BCH + bb2) * NPADC + t0 + tt] = (double)ut[tt][bb2];
            }
            __syncthreads();
        }
        return;
    }
    if (tid >= 64) return;                // gscan role: wave 0 only, no barriers
    int lane = tid;
    int b = blockIdx.x;
    double run = (lane == 0) ? 1.0 : 0.0;
    double gp = (lane < KP) ? gpoly[((size_t)b * NG + NG - 1) * KP + lane] : 0.0;
    for (int g = NG - 1; g >= 0; --g) {
        if (lane < KP) gcarry[((size_t)b * NG + g) * KP + lane] = run;
        double gpn = (g > 0 && lane < KP) ? gpoly[((size_t)b * NG + g - 1) * KP + lane] : 0.0;
        run = conv33_rb(run, gp);
        gp = gpn;
    }
    if (lane < KP) eZ[(size_t)b * KP + lane] = run;   // e_0..e_K of all items
}

// ---- kernel 3: backward sfx sweep fused with sampling (scalar-pipe broadcasts).
//      Bitset map kept as two 32-bit halves; during j>=32 the low half is
//      provably zero in every lane, so only the high half is updated
//      (straight-line, branch-free, bit-identical).
//      + marginal rows as extra grid blocks (role by blockIdx).
__global__ void k_backward(const double* __restrict__ X, const double* __restrict__ sfxI,
                           const double* __restrict__ gcarry, const double* __restrict__ UT,
                           const double* __restrict__ eZ,
                           unsigned long long* __restrict__ masks, int* __restrict__ tab,
                           float* __restrict__ outMarg) {
    const int NCMP = BCH * MSEG / 4;                 // 4096 compute blocks
    if ((int)blockIdx.x >= NCMP) {
        // ---- marginal role: one output row per block
        __shared__ double e[KP];
        __shared__ double invZ;
        int q = blockIdx.x - NCMP;                   // b*NMAXC + i
        int b = q >> 8, i = q & (NMAXC - 1);
        int j = threadIdx.x;                         // 256
        if (j < KP) e[j] = eZ[(size_t)b * KP + j];
        __syncthreads();
        if (j == 0) invZ = 1.0 / e[KK];
        __syncthreads();
        float v = 0.0f;
        if (i != j) {
            int t = (j > i) ? (OFFS(i) + j - i - 1) : (OFFS(j) + i - j - 1);
            double xv = X[(size_t)b * NPADC + t];
            double f = 1.0;
#pragma unroll
            for (int k = 1; k < KK; ++k) f = fma(-xv, f, e[k]);
            v = (float)(xv * f * invZ);
        }
        outMarg[((size_t)b * NMAXC + i) * NMAXC + j] = v;
        return;
    }
    int lane = threadIdx.x & 63;
    int blk = blockIdx.x * 4 + (threadIdx.x >> 6);   // b*MSEG + m
    int ublk = __builtin_amdgcn_readfirstlane(blk);  // wave-uniform -> scalar loads
    int b = ublk >> 9, m = ublk & (MSEG - 1);
    const double* xp  = X  + (size_t)b * NPADC + (size_t)m * LSEG;
    const double* u0p = UT + ((size_t)0 * BCH + b) * NPADC + (size_t)m * LSEG;
    const double* u1p = UT + ((size_t)1 * BCH + b) * NPADC + (size_t)m * LSEG;
    double c;
    if (m + 1 == MSEG) {
        c = (lane == 0) ? 1.0 : 0.0;
    } else {
        double a  = (lane < KP) ? sfxI[((size_t)b * MSEG + m + 1) * KP + lane] : 0.0;
        double cg = (lane < KP) ? gcarry[((size_t)b * NG + (m + 1) / GSZ) * KP + lane] : 0.0;
        c = conv33_rb(cg, a);             // same op order as round-7 k_chkpt
        c = (lane < KP) ? c : 0.0;        // keep lanes>=33 identical to prior rounds
    }
    unsigned B0h = 0, B0l = 0, B1h = 0, B1l = 0;
#pragma unroll
    for (int j = LSEG - 1; j >= 32; --j) {           // hi half: low words are 0
        double xj  = xp[j];                          // s_load (uniform addr)
        double ud0 = u0p[j];                         // s_load
        double ud1 = u1p[j];                         // s_load
        double up = dpp_shr1_d(c);                   // sfx[j+1][lane-1], lane0 -> 0
        double rhs = xj * up;
        double cn = fma(xj, up, c);                  // sfx[j][lane]
        bool i0 = (ud0 * cn < rhs);                  // lane0: rhs==0 -> false
        bool i1 = (ud1 * cn < rhs);
        unsigned bit = 1u << (j - 32);
        unsigned s0 = dpp_shr1_u(B0h) | bit;
        unsigned s1 = dpp_shr1_u(B1h) | bit;
        if (i0) B0h = s0;
        if (i1) B1h = s1;
        c = cn;
    }
#pragma unroll
    for (int j = 31; j >= 0; --j) {                  // lo half: full 64-bit map
        double xj  = xp[j];
        double ud0 = u0p[j];
        double ud1 = u1p[j];
        double up = dpp_shr1_d(c);
        double rhs = xj * up;
        double cn = fma(xj, up, c);
        bool i0 = (ud0 * cn < rhs);
        bool i1 = (ud1 * cn < rhs);
        unsigned bit = 1u << j;
        unsigned t0h = dpp_shr1_u(B0h), t0l = dpp_shr1_u(B0l) | bit;
        unsigned t1h = dpp_shr1_u(B1h), t1l = dpp_shr1_u(B1l) | bit;
        if (i0) { B0h = t0h; B0l = t0l; }
        if (i1) { B1h = t1h; B1l = t1l; }
        c = cn;
    }
    unsigned long long B0 = ((unsigned long long)B0h << 32) | B0l;
    unsigned long long B1 = ((unsigned long long)B1h << 32) | B1l;
    size_t sb0 = (size_t)blk;
    size_t sb1 = (size_t)BCH * MSEG + blk;
    masks[sb0 * LSEG + lane] = B0;                   // state-major realized bitsets
    masks[sb1 * LSEG + lane] = B1;
    if (lane < KP) {
        int S0 = lane - (__popc(B0l) + __popc(B0h));
        int S1 = lane - (__popc(B1l) + __popc(B1h));
        tab[sb0 * KP + lane] = S0;
        tab[sb1 * KP + lane] = S1;
    }
}

// ---- kernel 4: fused compose + mask emission, ONE block per chain sb
//      (non-redundant: compose runs exactly once per sb).
__global__ void __launch_bounds__(1024) k_emitc(const int* __restrict__ tab,
                                                const unsigned long long* __restrict__ masks,
                                                float* __restrict__ outMask) {
    __shared__ int gtab[NG][KP];
    __shared__ int gent[NG];
    __shared__ unsigned long long bf[MSEG];
    int sb = blockIdx.x;                  // s*BCH + b
    int tid = threadIdx.x;                // 1024
    int w = tid >> 6, lane = tid & 63;
    int tv[GSZ];
    const int* base = tab + ((size_t)sb * MSEG + w * GSZ) * KP;
#pragma unroll
    for (int i = 0; i < GSZ; ++i)
        tv[i] = (lane < KP) ? base[i * KP + lane] : 0;
    int T = lane;                         // compose this wave's 32 segment maps
#pragma unroll
    for (int i = 0; i < GSZ; ++i)
        T = __shfl(tv[i], T, 64);
    if (lane < KP) gtab[w][lane] = T;
    __syncthreads();
    if (tid == 0) {
        int r = KK;
        for (int g = 0; g < NG; ++g) { gent[g] = r; r = gtab[g][r]; }
    }
    __syncthreads();
    int r = __builtin_amdgcn_readfirstlane(gent[w]);
#pragma unroll
    for (int i = 0; i < GSZ; ++i) {       // walk group w; gather realized bitsets
        int seg = w * GSZ + i;
        unsigned long long mv = masks[((size_t)sb * MSEG + seg) * LSEG + r];  // uniform
        if (lane == 0) bf[seg] = mv;
        r = __builtin_amdgcn_readlane(tv[i], r);
    }
    __syncthreads();
    // emit 256 rows: wave w emits rows w*16 .. w*16+15, float4 stores
#pragma unroll
    for (int rr = 0; rr < 16; ++rr) {
        int i = w * 16 + rr;
        float4 v4;
        float* pv = (float*)&v4;
#pragma unroll
        for (int jj = 0; jj < 4; ++jj) {
            int j = lane * 4 + jj;
            float v = 0.0f;
            if (j > i) {
                int t = OFFS(i) + j - i - 1;
                v = (float)((bf[t >> 6] >> (t & 63)) & 1ull);
            } else if (j < i) {
                int t = OFFS(j) + i - j - 1;
                v = (float)((bf[t >> 6] >> (t & 63)) & 1ull);
            }
            pv[jj] = v;
        }
        *reinterpret_cast<float4*>(&outMask[((size_t)sb * NMAXC + i) * NMAXC + lane * 4]) = v4;
    }
}

extern "C" void kernel_launch(void* const* d_in, const int* in_sizes, int n_in,
                              void* d_out, int out_size, void* d_ws, size_t ws_size,
                              hipStream_t stream) {
    const float* scores = (const float*)d_in[0];
    const float* uniforms = (const float*)d_in[1];

    char* ws = (char*)d_ws;
    size_t off = 0;
    auto alloc = [&](size_t bytes) {
        void* p = ws + off;
        off += (bytes + 255) & ~(size_t)255;
        return p;
    };
    double* X      = (double*)alloc((size_t)BCH * NPADC * 8);
    double* UT     = (double*)alloc((size_t)SS * BCH * NPADC * 8);
    double* sfxI   = (double*)alloc((size_t)BCH * MSEG * KP * 8);
    double* gpoly  = (double*)alloc((size_t)BCH * NG * KP * 8);
    double* gcarry = (double*)alloc((size_t)BCH * NG * KP * 8);
    double* eZ     = (double*)alloc((size_t)BCH * KP * 8);
    unsigned long long* masks = (unsigned long long*)alloc((size_t)SS * BCH * MSEG * LSEG * 8);
    int* tab       = (int*)alloc((size_t)SS * BCH * MSEG * KP * 4);
    if (off > ws_size) return;            // ~50 MB

    float* outMask = (float*)d_out;
    float* outMarg = (float*)d_out + (size_t)SS * BCH * NMAXC * NMAXC;

    k_prepscan<<<BCH * NG, 1024, 0, stream>>>(scores, X, sfxI, gpoly);
    k_gscan<<<BCH + 256, 1024, 0, stream>>>(uniforms, gpoly, gcarry, eZ, UT);
    k_backward<<<BCH * MSEG / 4 + BCH * NMAXC, 256, 0, stream>>>(
        X, sfxI, gcarry, UT, eZ, masks, tab, outMarg);
    k_emitc<<<SS * BCH, 1024, 0, stream>>>(tab, masks, outMask);
}

// Round 22
// 114.265 us; speedup vs baseline: 1.1045x; 1.1045x over previous
//
#include <hip/hip_runtime.h>

#define KK 32
#define KP 33
#define NMAXC 256
#define BCH 32            // bsz * ENS
#define NPADC 32768
#define TARGETC 32640
#define LSEG 64           // items per segment
#define MSEG 512          // NPADC / LSEG
#define GSZ 32            // segments per group
#define NG 16             // MSEG / GSZ
#define SS 2

#define OFFS(i) ((i)*255 - (i)*((i)-1)/2)

// ---- cross-lane helpers on the VALU pipe (no ds_bpermute) ----
__device__ __forceinline__ int dpp_shr1_i(int v) {
    // wave_shr:1 (0x138), bound_ctrl=1 -> lane 0 receives 0
    return __builtin_amdgcn_mov_dpp(v, 0x138, 0xf, 0xf, true);
}
__device__ __forceinline__ unsigned dpp_shr1_u(unsigned v) {
    return (unsigned)dpp_shr1_i((int)v);
}
__device__ __forceinline__ double dpp_shr1_d(double v) {
    union { double d; int i[2]; } u; u.d = v;
    u.i[0] = dpp_shr1_i(u.i[0]);
    u.i[1] = dpp_shr1_i(u.i[1]);
    return u.d;
}
__device__ __forceinline__ double readlane_d(double v, int l) {
    union { double d; int i[2]; } u; u.d = v;
    union { double d; int i[2]; } r;
    r.i[0] = __builtin_amdgcn_readlane(u.i[0], l);
    r.i[1] = __builtin_amdgcn_readlane(u.i[1], l);
    return r.d;
}

__device__ __forceinline__ void decode_ij(int t, int& oi, int& oj) {
    int ii = (int)((511.0 - sqrt(511.0 * 511.0 - 8.0 * (double)t)) * 0.5);
    if (ii < 0) ii = 0;
    if (ii > 254) ii = 254;
    while (ii < 254 && OFFS(ii + 1) <= t) ++ii;
    while (ii > 0 && OFFS(ii) > t) --ii;
    oi = ii;
    oj = t - OFFS(ii) + ii + 1;
}

// 33-point truncated polynomial product: out[r] = sum_j a[j]*b[r-j].
__device__ __forceinline__ double conv33_rb(double a_dep, double b_rot) {
    double s0 = 0.0, s1 = 0.0, s2 = 0.0, s3 = 0.0;
    double brot = b_rot;
#pragma unroll
    for (int j = 0; j < KP; ++j) {
        double aj = readlane_d(a_dep, j);
        switch (j & 3) {
            case 0: s0 = fma(aj, brot, s0); break;
            case 1: s1 = fma(aj, brot, s1); break;
            case 2: s2 = fma(aj, brot, s2); break;
            default: s3 = fma(aj, brot, s3); break;
        }
        brot = dpp_shr1_d(brot);
    }
    return (s0 + s1) + (s2 + s3);
}

// ---- kernel 1: fused exp(theta) + segment polys + within-group suffix scan
__global__ void k_prepscan(const float* __restrict__ sc, double* __restrict__ X,
                           double* __restrict__ sfxI, double* __restrict__ gpoly) {
    __shared__ double bpl[GSZ][KP];       // 8448 B
    int tid = threadIdx.x;                // 1024
    int lane = tid & 63;
    int w = tid >> 6;                     // 0..15
    int blk = blockIdx.x;                 // b*NG + g
    int b = blk / NG, g = blk % NG;
#pragma unroll
    for (int q = 0; q < 2; ++q) {
        int seg = g * GSZ + w * 2 + q;    // segment index within chain b
        int t = seg * LSEG + lane;
        double x = 0.0;
        if (t < TARGETC) {
            int i, j;
            decode_ij(t, i, j);
            double th = (double)sc[((size_t)b * NMAXC + i) * NMAXC + j] +
                        (double)sc[((size_t)b * NMAXC + j) * NMAXC + i];
            x = exp(th);
        }
        X[(size_t)b * NPADC + t] = x;
        double c = (lane == 0) ? 1.0 : 0.0;
#pragma unroll
        for (int j = 0; j < LSEG; ++j) {
            double xj = readlane_d(x, j);
            double up = dpp_shr1_d(c);    // lane0 -> 0
            c = fma(xj, up, c);
        }
        if (lane < KP) bpl[w * 2 + q][lane] = c;
    }
    __syncthreads();
    if (w == 0) {                         // phase B: serial suffix scan, old order
        double run = (lane == 0) ? 1.0 : 0.0;
        for (int i = GSZ - 1; i >= 0; --i) {
            double bp = (lane < KP) ? bpl[i][lane] : 0.0;
            run = conv33_rb(run, bp);
            if (lane < KP) sfxI[((size_t)b * MSEG + g * GSZ + i) * KP + lane] = run;
        }
        if (lane < KP) gpoly[(size_t)blk * KP + lane] = run;
    }
}

// ---- kernel 2: two roles.
//      blockIdx.x < BCH : suffix scan over group polys + full Z poly (wave 0)
//      blockIdx.x >= BCH: coalesced LDS-tile U transpose/widen -> UT[s][b][t]
__global__ void __launch_bounds__(1024) k_gscan(
        const float* __restrict__ U, const double* __restrict__ gpoly,
        double* __restrict__ gcarry, double* __restrict__ eZ,
        double* __restrict__ UT) {
    __shared__ float ut[LSEG][KP];        // 8448 B (transpose role)
    int tid = threadIdx.x;
    if ((int)blockIdx.x >= BCH) {
        // ---- transpose role: 4 tiles of 64t x 32b, coalesced both sides ----
        int q = blockIdx.x - BCH;         // 0..255
#pragma unroll
        for (int k = 0; k < 4; ++k) {
            int p = q * 4 + k;            // tile id: s = p>>9, t0 = (p&511)*64
            int s = p >> 9, t0 = (p & 511) * LSEG;
            int e = tid * 2;              // load: 2 consecutive f32 per thread
            int tr = e >> 5, bb = e & 31;
            float2 v = *reinterpret_cast<const float2*>(
                &U[((size_t)s * NPADC + t0 + tr) * BCH + bb]);
            ut[tr][bb] = v.x;
            ut[tr][bb + 1] = v.y;
            __syncthreads();
#pragma unroll
            for (int kk = 0; kk < 2; ++kk) {   // store: 2 f64 per thread, coalesced
                int e2 = tid + kk * 1024;
                int bb2 = e2 >> 6, tt = e2 & 63;
                UT[((size_t)s * BCH + bb2) * NPADC + t0 + tt] = (double)ut[tt][bb2];
            }
            __syncthreads();
        }
        return;
    }
    if (tid >= 64) return;                // gscan role: wave 0 only, no barriers
    int lane = tid;
    int b = blockIdx.x;
    double run = (lane == 0) ? 1.0 : 0.0;
    double gp = (lane < KP) ? gpoly[((size_t)b * NG + NG - 1) * KP + lane] : 0.0;
    for (int g = NG - 1; g >= 0; --g) {
        if (lane < KP) gcarry[((size_t)b * NG + g) * KP + lane] = run;
        double gpn = (g > 0 && lane < KP) ? gpoly[((size_t)b * NG + g - 1) * KP + lane] : 0.0;
        run = conv33_rb(run, gp);
        gp = gpn;
    }
    if (lane < KP) eZ[(size_t)b * KP + lane] = run;   // e_0..e_K of all items
}

// ---- kernel 3: backward sfx sweep fused with sampling (scalar-pipe broadcasts).
//      Bitset map kept as two 32-bit halves; during j>=32 the low half is
//      provably zero in every lane, so only the high half is updated
//      (straight-line, branch-free, bit-identical).
//      + marginal rows as extra grid blocks (role by blockIdx).
__global__ void k_backward(const double* __restrict__ X, const double* __restrict__ sfxI,
                           const double* __restrict__ gcarry, const double* __restrict__ UT,
                           const double* __restrict__ eZ,
                           unsigned long long* __restrict__ masks, int* __restrict__ tab,
                           float* __restrict__ outMarg) {
    const int NCMP = BCH * MSEG / 4;                 // 4096 compute blocks
    if ((int)blockIdx.x >= NCMP) {
        // ---- marginal role: one output row per block
        __shared__ double e[KP];
        __shared__ double invZ;
        int q = blockIdx.x - NCMP;                   // b*NMAXC + i
        int b = q >> 8, i = q & (NMAXC - 1);
        int j = threadIdx.x;                         // 256
        if (j < KP) e[j] = eZ[(size_t)b * KP + j];
        __syncthreads();
        if (j == 0) invZ = 1.0 / e[KK];
        __syncthreads();
        float v = 0.0f;
        if (i != j) {
            int t = (j > i) ? (OFFS(i) + j - i - 1) : (OFFS(j) + i - j - 1);
            double xv = X[(size_t)b * NPADC + t];
            double f = 1.0;
#pragma unroll
            for (int k = 1; k < KK; ++k) f = fma(-xv, f, e[k]);
            v = (float)(xv * f * invZ);
        }
        outMarg[((size_t)b * NMAXC + i) * NMAXC + j] = v;
        return;
    }
    int lane = threadIdx.x & 63;
    int blk = blockIdx.x * 4 + (threadIdx.x >> 6);   // b*MSEG + m
    int ublk = __builtin_amdgcn_readfirstlane(blk);  // wave-uniform -> scalar loads
    int b = ublk >> 9, m = ublk & (MSEG - 1);
    const double* xp  = X  + (size_t)b * NPADC + (size_t)m * LSEG;
    const double* u0p = UT + ((size_t)0 * BCH + b) * NPADC + (size_t)m * LSEG;
    const double* u1p = UT + ((size_t)1 * BCH + b) * NPADC + (size_t)m * LSEG;
    double c;
    if (m + 1 == MSEG) {
        c = (lane == 0) ? 1.0 : 0.0;
    } else {
        double a  = (lane < KP) ? sfxI[((size_t)b * MSEG + m + 1) * KP + lane] : 0.0;
        double cg = (lane < KP) ? gcarry[((size_t)b * NG + (m + 1) / GSZ) * KP + lane] : 0.0;
        c = conv33_rb(cg, a);             // same op order as round-7 k_chkpt
        c = (lane < KP) ? c : 0.0;        // keep lanes>=33 identical to prior rounds
    }
    unsigned B0h = 0, B0l = 0, B1h = 0, B1l = 0;
#pragma unroll
    for (int j = LSEG - 1; j >= 32; --j) {           // hi half: low words are 0
        double xj  = xp[j];                          // s_load (uniform addr)
        double ud0 = u0p[j];                         // s_load
        double ud1 = u1p[j];                         // s_load
        double up = dpp_shr1_d(c);                   // sfx[j+1][lane-1], lane0 -> 0
        double rhs = xj * up;
        double cn = fma(xj, up, c);                  // sfx[j][lane]
        bool i0 = (ud0 * cn < rhs);                  // lane0: rhs==0 -> false
        bool i1 = (ud1 * cn < rhs);
        unsigned bit = 1u << (j - 32);
        unsigned s0 = dpp_shr1_u(B0h) | bit;
        unsigned s1 = dpp_shr1_u(B1h) | bit;
        if (i0) B0h = s0;
        if (i1) B1h = s1;
        c = cn;
    }
#pragma unroll
    for (int j = 31; j >= 0; --j) {                  // lo half: full 64-bit map
        double xj  = xp[j];
        double ud0 = u0p[j];
        double ud1 = u1p[j];
        double up = dpp_shr1_d(c);
        double rhs = xj * up;
        double cn = fma(xj, up, c);
        bool i0 = (ud0 * cn < rhs);
        bool i1 = (ud1 * cn < rhs);
        unsigned bit = 1u << j;
        unsigned t0h = dpp_shr1_u(B0h), t0l = dpp_shr1_u(B0l) | bit;
        unsigned t1h = dpp_shr1_u(B1h), t1l = dpp_shr1_u(B1l) | bit;
        if (i0) { B0h = t0h; B0l = t0l; }
        if (i1) { B1h = t1h; B1l = t1l; }
        c = cn;
    }
    unsigned long long B0 = ((unsigned long long)B0h << 32) | B0l;
    unsigned long long B1 = ((unsigned long long)B1h << 32) | B1l;
    size_t sb0 = (size_t)blk;
    size_t sb1 = (size_t)BCH * MSEG + blk;
    masks[sb0 * LSEG + lane] = B0;                   // state-major realized bitsets
    masks[sb1 * LSEG + lane] = B1;
    if (lane < KP) {
        int S0 = lane - (__popc(B0l) + __popc(B0h));
        int S1 = lane - (__popc(B1l) + __popc(B1h));
        tab[sb0 * KP + lane] = S0;
        tab[sb1 * KP + lane] = S1;
    }
}

// ---- kernel 4: hierarchical compose; per-wave tables kept in VGPRs
__global__ void __launch_bounds__(1024) k_compose(const int* __restrict__ tab,
                                                  int* __restrict__ rent) {
    __shared__ int gtab[NG][KP];
    __shared__ int gent[NG];
    int sb = blockIdx.x;                  // s*BCH + b
    int tid = threadIdx.x;                // 1024
    int w = tid >> 6, lane = tid & 63;
    int tv[GSZ];
    const int* base = tab + ((size_t)sb * MSEG + w * GSZ) * KP;
#pragma unroll
    for (int i = 0; i < GSZ; ++i)
        tv[i] = (lane < KP) ? base[i * KP + lane] : 0;
    int T = lane;                         // compose this wave's 32 segment maps
#pragma unroll
    for (int i = 0; i < GSZ; ++i)
        T = __shfl(tv[i], T, 64);
    if (lane < KP) gtab[w][lane] = T;
    __syncthreads();
    if (tid == 0) {
        int r = KK;
        for (int g = 0; g < NG; ++g) { gent[g] = r; r = gtab[g][r]; }
    }
    __syncthreads();
    int r = __builtin_amdgcn_readfirstlane(gent[w]);
    int rv = 0;
#pragma unroll
    for (int i = 0; i < GSZ; ++i) {       // scalar walk via readlane (no LDS chain)
        if (lane == i) rv = r;
        r = __builtin_amdgcn_readlane(tv[i], r);
    }
    if (lane < GSZ) rent[(size_t)sb * MSEG + w * GSZ + lane] = rv;
}

// ---- kernel 5: mask emission; realized bitset gathered per sb, float4 stores
__global__ void k_emit(const unsigned long long* __restrict__ masks,
                       const int* __restrict__ rent, float* __restrict__ outMask) {
    __shared__ unsigned long long bf[MSEG];
    int sb = blockIdx.y;
    int tid = threadIdx.x;                // 256
    int s0 = tid, s1 = tid + 256;
    bf[s0] = masks[((size_t)sb * MSEG + s0) * LSEG + rent[(size_t)sb * MSEG + s0]];
    bf[s1] = masks[((size_t)sb * MSEG + s1) * LSEG + rent[(size_t)sb * MSEG + s1]];
    __syncthreads();
    int i = blockIdx.x * 4 + (tid >> 6);
    int lane = tid & 63;
    float4 v4;
    float* pv = (float*)&v4;
#pragma unroll
    for (int jj = 0; jj < 4; ++jj) {
        int j = lane * 4 + jj;
        float v = 0.0f;
        if (j > i) {
            int t = OFFS(i) + j - i - 1;
            v = (float)((bf[t >> 6] >> (t & 63)) & 1ull);
        } else if (j < i) {
            int t = OFFS(j) + i - j - 1;
            v = (float)((bf[t >> 6] >> (t & 63)) & 1ull);
        }
        pv[jj] = v;
    }
    *reinterpret_cast<float4*>(&outMask[((size_t)sb * NMAXC + i) * NMAXC + lane * 4]) = v4;
}

extern "C" void kernel_launch(void* const* d_in, const int* in_sizes, int n_in,
                              void* d_out, int out_size, void* d_ws, size_t ws_size,
                              hipStream_t stream) {
    const float* scores = (const float*)d_in[0];
    const float* uniforms = (const float*)d_in[1];

    char* ws = (char*)d_ws;
    size_t off = 0;
    auto alloc = [&](size_t bytes) {
        void* p = ws + off;
        off += (bytes + 255) & ~(size_t)255;
        return p;
    };
    double* X      = (double*)alloc((size_t)BCH * NPADC * 8);
    double* UT     = (double*)alloc((size_t)SS * BCH * NPADC * 8);
    double* sfxI   = (double*)alloc((size_t)BCH * MSEG * KP * 8);
    double* gpoly  = (double*)alloc((size_t)BCH * NG * KP * 8);
    double* gcarry = (double*)alloc((size_t)BCH * NG * KP * 8);
    double* eZ     = (double*)alloc((size_t)BCH * KP * 8);
    unsigned long long* masks = (unsigned long long*)alloc((size_t)SS * BCH * MSEG * LSEG * 8);
    int* tab       = (int*)alloc((size_t)SS * BCH * MSEG * KP * 4);
    int* rent      = (int*)alloc((size_t)SS * BCH * MSEG * 4);
    if (off > ws_size) return;            // ~50 MB

    float* outMask = (float*)d_out;
    float* outMarg = (float*)d_out + (size_t)SS * BCH * NMAXC * NMAXC;

    k_prepscan<<<BCH * NG, 1024, 0, stream>>>(scores, X, sfxI, gpoly);
    k_gscan<<<BCH + 256, 1024, 0, stream>>>(uniforms, gpoly, gcarry, eZ, UT);
    k_backward<<<BCH * MSEG / 4 + BCH * NMAXC, 256, 0, stream>>>(
        X, sfxI, gcarry, UT, eZ, masks, tab, outMarg);
    k_compose<<<SS * BCH, 1024, 0, stream>>>(tab, rent);
    k_emit<<<dim3(NMAXC / 4, SS * BCH), 256, 0, stream>>>(masks, rent, outMask);
}